// Round 2
// baseline (114.038 us; speedup 1.0000x reference)
//
#include <hip/hip_runtime.h>

// LatticeGaussian: out = W @ U - U, W[i,j] = exp(-0.5*||ref_i - ref_j||^2)
// N=8192, C=16, D=5, fp32. Exact pairwise evaluation (compute-bound, O(N^2)).
//
// Structure:
//   lg_pre:    sqh[j] = -0.5*|ref_j|^2                     (32 blocks)
//   lg_main:   32 i-chunks x 32 j-segments = 1024 blocks x 256 thr.
//              Thread owns row i, accumulates C=16 channels in regs over
//              its 256-j segment. Gram-trick exponent: e = a_i + sqh[j]
//              + sum_d r_d*s_d  (1 add + 5 FMA), w = __expf(e).
//              Partials -> ws[seg][i][c] (16 MB), no atomics.
//   lg_reduce: out[i][c] = -U[i][c] + sum_seg part[seg][i][c].
// Fallback (ws too small): init out=-U, direct-distance kernel + atomicAdd.

#define N_ROWS 8192
#define C_CH   16
#define D_DIM  5
#define TPB    256
#define NSEG   32
#define NIB    (N_ROWS / TPB)   // 32 i-chunks
#define JPB    (N_ROWS / NSEG)  // 256 j per segment

__global__ __launch_bounds__(TPB) void lg_pre(const float* __restrict__ ref,
                                              float* __restrict__ sqh) {
    const int j = blockIdx.x * TPB + threadIdx.x;
    float s = 0.0f;
#pragma unroll
    for (int d = 0; d < D_DIM; ++d) {
        const float v = ref[j * D_DIM + d];
        s = fmaf(v, v, s);
    }
    sqh[j] = -0.5f * s;
}

__global__ __launch_bounds__(TPB) void lg_main(const float* __restrict__ U,
                                               const float* __restrict__ ref,
                                               const float* __restrict__ sqh,
                                               float* __restrict__ part) {
    const int bid = blockIdx.x;
    const int ib  = bid % NIB;
    const int seg = bid / NIB;
    const int i   = ib * TPB + threadIdx.x;

    const float r0 = ref[i * D_DIM + 0];
    const float r1 = ref[i * D_DIM + 1];
    const float r2 = ref[i * D_DIM + 2];
    const float r3 = ref[i * D_DIM + 3];
    const float r4 = ref[i * D_DIM + 4];
    float ai = r0 * r0;
    ai = fmaf(r1, r1, ai);
    ai = fmaf(r2, r2, ai);
    ai = fmaf(r3, r3, ai);
    ai = fmaf(r4, r4, ai);
    ai = -0.5f * ai;

    float acc[C_CH];
#pragma unroll
    for (int c = 0; c < C_CH; ++c) acc[c] = 0.0f;

    const float4* __restrict__ U4 = reinterpret_cast<const float4*>(U);

    const int j0 = seg * JPB;
#pragma unroll 8
    for (int j = j0; j < j0 + JPB; ++j) {
        // j is block-uniform: these should scalarize (s_load / broadcast).
        const float s0 = ref[j * D_DIM + 0];
        const float s1 = ref[j * D_DIM + 1];
        const float s2 = ref[j * D_DIM + 2];
        const float s3 = ref[j * D_DIM + 3];
        const float s4 = ref[j * D_DIM + 4];

        float e = ai + sqh[j];          // -0.5(|ri|^2 + |rj|^2)
        e = fmaf(r0, s0, e);
        e = fmaf(r1, s1, e);
        e = fmaf(r2, s2, e);
        e = fmaf(r3, s3, e);
        e = fmaf(r4, s4, e);            // e = -0.5*d^2 (gram trick)
        const float w = __expf(e);

        const float4 u0 = U4[j * 4 + 0];
        const float4 u1 = U4[j * 4 + 1];
        const float4 u2 = U4[j * 4 + 2];
        const float4 u3 = U4[j * 4 + 3];

        acc[0]  = fmaf(w, u0.x, acc[0]);   acc[1]  = fmaf(w, u0.y, acc[1]);
        acc[2]  = fmaf(w, u0.z, acc[2]);   acc[3]  = fmaf(w, u0.w, acc[3]);
        acc[4]  = fmaf(w, u1.x, acc[4]);   acc[5]  = fmaf(w, u1.y, acc[5]);
        acc[6]  = fmaf(w, u1.z, acc[6]);   acc[7]  = fmaf(w, u1.w, acc[7]);
        acc[8]  = fmaf(w, u2.x, acc[8]);   acc[9]  = fmaf(w, u2.y, acc[9]);
        acc[10] = fmaf(w, u2.z, acc[10]);  acc[11] = fmaf(w, u2.w, acc[11]);
        acc[12] = fmaf(w, u3.x, acc[12]);  acc[13] = fmaf(w, u3.y, acc[13]);
        acc[14] = fmaf(w, u3.z, acc[14]);  acc[15] = fmaf(w, u3.w, acc[15]);
    }

    float4* p4 = reinterpret_cast<float4*>(part + ((size_t)seg * N_ROWS + i) * C_CH);
    p4[0] = make_float4(acc[0], acc[1], acc[2], acc[3]);
    p4[1] = make_float4(acc[4], acc[5], acc[6], acc[7]);
    p4[2] = make_float4(acc[8], acc[9], acc[10], acc[11]);
    p4[3] = make_float4(acc[12], acc[13], acc[14], acc[15]);
}

__global__ __launch_bounds__(TPB) void lg_reduce(const float* __restrict__ U,
                                                 const float* __restrict__ part,
                                                 float* __restrict__ out) {
    const int t = blockIdx.x * TPB + threadIdx.x;  // float4 index, 32768 total
    const float4 u = reinterpret_cast<const float4*>(U)[t];
    float4 s = make_float4(-u.x, -u.y, -u.z, -u.w);
    const float4* p = reinterpret_cast<const float4*>(part);
#pragma unroll
    for (int seg = 0; seg < NSEG; ++seg) {
        const float4 v = p[(size_t)seg * (N_ROWS * C_CH / 4) + t];
        s.x += v.x; s.y += v.y; s.z += v.z; s.w += v.w;
    }
    reinterpret_cast<float4*>(out)[t] = s;
}

// ---- Fallback path (ws too small): direct distance + atomics ----

__global__ __launch_bounds__(TPB) void lg_init(const float* __restrict__ U,
                                               float* __restrict__ out) {
    const int idx = blockIdx.x * TPB + threadIdx.x;
    if (idx < N_ROWS * C_CH) out[idx] = -U[idx];
}

__global__ __launch_bounds__(TPB) void lg_main_atomic(const float* __restrict__ U,
                                                      const float* __restrict__ ref,
                                                      float* __restrict__ out) {
    const int bid = blockIdx.x;
    const int ib  = bid % NIB;
    const int seg = bid / NIB;
    const int i   = ib * TPB + threadIdx.x;

    const float r0 = ref[i * D_DIM + 0];
    const float r1 = ref[i * D_DIM + 1];
    const float r2 = ref[i * D_DIM + 2];
    const float r3 = ref[i * D_DIM + 3];
    const float r4 = ref[i * D_DIM + 4];

    float acc[C_CH];
#pragma unroll
    for (int c = 0; c < C_CH; ++c) acc[c] = 0.0f;

    const float4* __restrict__ U4 = reinterpret_cast<const float4*>(U);
    const int j0 = seg * JPB;
#pragma unroll 4
    for (int j = j0; j < j0 + JPB; ++j) {
        const float d0 = r0 - ref[j * D_DIM + 0];
        const float d1 = r1 - ref[j * D_DIM + 1];
        const float d2 = r2 - ref[j * D_DIM + 2];
        const float d3 = r3 - ref[j * D_DIM + 3];
        const float d4 = r4 - ref[j * D_DIM + 4];
        float dsq = d0 * d0;
        dsq = fmaf(d1, d1, dsq); dsq = fmaf(d2, d2, dsq);
        dsq = fmaf(d3, d3, dsq); dsq = fmaf(d4, d4, dsq);
        const float w = __expf(-0.5f * dsq);

        const float4 u0 = U4[j * 4 + 0];
        const float4 u1 = U4[j * 4 + 1];
        const float4 u2 = U4[j * 4 + 2];
        const float4 u3 = U4[j * 4 + 3];
        acc[0]  = fmaf(w, u0.x, acc[0]);   acc[1]  = fmaf(w, u0.y, acc[1]);
        acc[2]  = fmaf(w, u0.z, acc[2]);   acc[3]  = fmaf(w, u0.w, acc[3]);
        acc[4]  = fmaf(w, u1.x, acc[4]);   acc[5]  = fmaf(w, u1.y, acc[5]);
        acc[6]  = fmaf(w, u1.z, acc[6]);   acc[7]  = fmaf(w, u1.w, acc[7]);
        acc[8]  = fmaf(w, u2.x, acc[8]);   acc[9]  = fmaf(w, u2.y, acc[9]);
        acc[10] = fmaf(w, u2.z, acc[10]);  acc[11] = fmaf(w, u2.w, acc[11]);
        acc[12] = fmaf(w, u3.x, acc[12]);  acc[13] = fmaf(w, u3.y, acc[13]);
        acc[14] = fmaf(w, u3.z, acc[14]);  acc[15] = fmaf(w, u3.w, acc[15]);
    }

    float* o = out + (size_t)i * C_CH;
#pragma unroll
    for (int c = 0; c < C_CH; ++c) atomicAdd(&o[c], acc[c]);
}

extern "C" void kernel_launch(void* const* d_in, const int* in_sizes, int n_in,
                              void* d_out, int out_size, void* d_ws, size_t ws_size,
                              hipStream_t stream) {
    const float* U   = (const float*)d_in[0];   // [8192,16]
    const float* ref = (const float*)d_in[1];   // [8192,5]
    float* out       = (float*)d_out;           // [8192,16]

    const size_t need = ((size_t)N_ROWS + (size_t)NSEG * N_ROWS * C_CH) * sizeof(float);
    if (ws_size >= need) {
        float* sqh  = (float*)d_ws;             // 8192 floats
        float* part = sqh + N_ROWS;             // 32*8192*16 floats
        hipLaunchKernelGGL(lg_pre, dim3(N_ROWS / TPB), dim3(TPB), 0, stream, ref, sqh);
        hipLaunchKernelGGL(lg_main, dim3(NIB * NSEG), dim3(TPB), 0, stream,
                           U, ref, sqh, part);
        hipLaunchKernelGGL(lg_reduce, dim3(N_ROWS * C_CH / 4 / TPB), dim3(TPB), 0,
                           stream, U, part, out);
    } else {
        hipLaunchKernelGGL(lg_init, dim3((N_ROWS * C_CH + TPB - 1) / TPB), dim3(TPB),
                           0, stream, U, out);
        hipLaunchKernelGGL(lg_main_atomic, dim3(NIB * NSEG), dim3(TPB), 0, stream,
                           U, ref, out);
    }
}